// Round 1
// baseline (2950.070 us; speedup 1.0000x reference)
//
#include <hip/hip_runtime.h>

#define N_NODES 100000
#define N_EDGES 640000
#define DIN 128
#define HDIM 128
#define DOUT 64

// ---------------- degree / dinv ----------------
__global__ void init_deg_kernel(float* deg, int n) {
    int i = blockIdx.x * 256 + threadIdx.x;
    if (i < n) deg[i] = 1.0f;   // self loop
}

__global__ void count_deg_kernel(const int* __restrict__ ei, float* deg, int ne) {
    int e = blockIdx.x * 256 + threadIdx.x;
    if (e < ne) atomicAdd(&deg[ei[ne + e]], 1.0f);   // dst side
}

__global__ void finalize_dinv_kernel(float* deg, int n) {
    int i = blockIdx.x * 256 + threadIdx.x;
    if (i < n) deg[i] = rsqrtf(deg[i]);
}

// ---------------- BN fold: scale = g*rsqrt(v+eps), shift = b - m*scale ----------------
__global__ void bn_prep_kernel(const float* __restrict__ g, const float* __restrict__ b,
                               const float* __restrict__ m, const float* __restrict__ v,
                               float* __restrict__ scale, float* __restrict__ shift) {
    int i = threadIdx.x;  // 128 threads
    float s = g[i] * rsqrtf(v[i] + 1e-5f);
    scale[i] = s;
    shift[i] = b[i] - m[i] * s;
}

// ---------------- GEMM with BN applied on input staging ----------------
// T[N][COUT] = (X*scale+shift) @ W,  X is [N][128], W is [128][COUT]
template<int COUT>
__global__ __launch_bounds__(256) void gemm_bn_kernel(
    const float* __restrict__ X, const float* __restrict__ scale,
    const float* __restrict__ shift, const float* __restrict__ W,
    float* __restrict__ T, int nrows)
{
    constexpr int CG  = COUT / 4;   // col groups of 4
    constexpr int RT  = 256 / CG;   // row-threads
    constexpr int RPT = 64 / RT;    // rows per thread
    __shared__ float xs[64][132];   // padded: bank-conflict-free

    int row0 = blockIdx.x * 64;
    int tid  = threadIdx.x;

    const float4* X4 = (const float4*)X;
    const float4* S4 = (const float4*)scale;
    const float4* H4 = (const float4*)shift;

    #pragma unroll
    for (int j = 0; j < 8; ++j) {           // 64*32 float4 / 256 threads
        int idx = tid + j * 256;
        int r = idx >> 5, c4 = idx & 31;
        int row = row0 + r;
        float4 v = make_float4(0.f, 0.f, 0.f, 0.f);
        if (row < nrows) v = X4[(size_t)row * 32 + c4];
        float4 s = S4[c4], h = H4[c4];
        xs[r][c4 * 4 + 0] = v.x * s.x + h.x;
        xs[r][c4 * 4 + 1] = v.y * s.y + h.y;
        xs[r][c4 * 4 + 2] = v.z * s.z + h.z;
        xs[r][c4 * 4 + 3] = v.w * s.w + h.w;
    }
    __syncthreads();

    int cg = tid % CG, rt = tid / CG;
    float acc[RPT][4];
    #pragma unroll
    for (int i = 0; i < RPT; ++i) {
        acc[i][0] = 0.f; acc[i][1] = 0.f; acc[i][2] = 0.f; acc[i][3] = 0.f;
    }

    const float4* W4 = (const float4*)W;
    for (int k = 0; k < 128; ++k) {
        float4 w = W4[k * CG + cg];
        #pragma unroll
        for (int i = 0; i < RPT; ++i) {
            float xv = xs[rt + i * RT][k];
            acc[i][0] += xv * w.x;
            acc[i][1] += xv * w.y;
            acc[i][2] += xv * w.z;
            acc[i][3] += xv * w.w;
        }
    }

    float4* T4 = (float4*)T;
    #pragma unroll
    for (int i = 0; i < RPT; ++i) {
        int row = row0 + rt + i * RT;
        if (row < nrows) {
            float4 o;
            o.x = acc[i][0]; o.y = acc[i][1]; o.z = acc[i][2]; o.w = acc[i][3];
            T4[(size_t)row * CG + cg] = o;
        }
    }
}

// ---------------- out[i] = T[i]*dinv[i]^2 + bias  (also initializes d_out) ----------------
template<int COUT>
__global__ void self_init_kernel(const float* __restrict__ T, const float* __restrict__ dinv,
                                 const float* __restrict__ bias, float* __restrict__ out, int n)
{
    constexpr int CG = COUT / 4;
    int gid = blockIdx.x * 256 + threadIdx.x;
    if (gid >= n * CG) return;
    int i = gid / CG, c = gid % CG;
    float di = dinv[i];
    float coef = di * di;
    float4 v = ((const float4*)T)[gid];
    float4 b = ((const float4*)bias)[c];
    float4 o;
    o.x = v.x * coef + b.x;
    o.y = v.y * coef + b.y;
    o.z = v.z * coef + b.z;
    o.w = v.w * coef + b.w;
    ((float4*)out)[gid] = o;
}

// ---------------- edge scatter: out[dst] += T[src] * dinv[src]*dinv[dst] ----------------
template<int COUT>
__global__ void scatter_kernel(const float* __restrict__ T, const float* __restrict__ dinv,
                               const int* __restrict__ ei, float* __restrict__ out, int ne)
{
    constexpr int CG = COUT / 4;
    int gid = blockIdx.x * 256 + threadIdx.x;
    if (gid >= ne * CG) return;
    int e = gid / CG, c = gid % CG;
    int s = ei[e], d = ei[ne + e];
    float coef = dinv[s] * dinv[d];
    float4 v = ((const float4*)T)[(size_t)s * CG + c];
    float* o = out + (size_t)d * COUT + c * 4;
    atomicAdd(o + 0, v.x * coef);
    atomicAdd(o + 1, v.y * coef);
    atomicAdd(o + 2, v.z * coef);
    atomicAdd(o + 3, v.w * coef);
}

__global__ void relu_kernel(float* __restrict__ x, int n4) {
    int gid = blockIdx.x * 256 + threadIdx.x;
    if (gid < n4) {
        float4 v = ((float4*)x)[gid];
        v.x = fmaxf(v.x, 0.f);
        v.y = fmaxf(v.y, 0.f);
        v.z = fmaxf(v.z, 0.f);
        v.w = fmaxf(v.w, 0.f);
        ((float4*)x)[gid] = v;
    }
}

extern "C" void kernel_launch(void* const* d_in, const int* in_sizes, int n_in,
                              void* d_out, int out_size, void* d_ws, size_t ws_size,
                              hipStream_t stream) {
    const float* x   = (const float*)d_in[0];
    const int*   ei  = (const int*)d_in[1];     // [2][E] int32
    const float* W1  = (const float*)d_in[4];
    const float* b1  = (const float*)d_in[5];
    const float* Wm  = (const float*)d_in[6];
    const float* bm  = (const float*)d_in[7];
    const float* W2  = (const float*)d_in[8];
    const float* b2  = (const float*)d_in[9];
    const float* bn1g = (const float*)d_in[10];
    const float* bn1b = (const float*)d_in[11];
    const float* bn1m = (const float*)d_in[12];
    const float* bn1v = (const float*)d_in[13];
    const float* bnmg = (const float*)d_in[14];
    const float* bnmb = (const float*)d_in[15];
    const float* bnmm = (const float*)d_in[16];
    const float* bnmv = (const float*)d_in[17];
    const float* bn2g = (const float*)d_in[18];
    const float* bn2b = (const float*)d_in[19];
    const float* bn2m = (const float*)d_in[20];
    const float* bn2v = (const float*)d_in[21];

    float* out  = (float*)d_out;
    float* res1 = out + (size_t)N_NODES * DOUT;
    float* res2 = res1 + (size_t)N_NODES * HDIM;

    float* T    = (float*)d_ws;                       // [N][128] scratch (51.2 MB)
    float* dinv = T + (size_t)N_NODES * HDIM;         // [N]
    float* sc1  = dinv + N_NODES;
    float* sh1  = sc1 + 128;
    float* scm  = sh1 + 128;
    float* shm  = scm + 128;
    float* sc2  = shm + 128;
    float* sh2  = sc2 + 128;

    int gN  = (N_NODES + 255) / 256;
    int gE  = (N_EDGES + 255) / 256;
    int gT  = (N_NODES + 63) / 64;                    // 1563 gemm blocks

    // degrees -> dinv
    init_deg_kernel<<<gN, 256, 0, stream>>>(dinv, N_NODES);
    count_deg_kernel<<<gE, 256, 0, stream>>>(ei, dinv, N_EDGES);
    finalize_dinv_kernel<<<gN, 256, 0, stream>>>(dinv, N_NODES);

    // BN folds
    bn_prep_kernel<<<1, 128, 0, stream>>>(bn1g, bn1b, bn1m, bn1v, sc1, sh1);
    bn_prep_kernel<<<1, 128, 0, stream>>>(bnmg, bnmb, bnmm, bnmv, scm, shm);
    bn_prep_kernel<<<1, 128, 0, stream>>>(bn2g, bn2b, bn2m, bn2v, sc2, sh2);

    int g128 = (N_NODES * 32 + 255) / 256;   // self_init/relu grid, COUT=128
    int s128 = (N_EDGES * 32 + 255) / 256;   // scatter grid, COUT=128
    int g64  = (N_NODES * 16 + 255) / 256;
    int s64  = (N_EDGES * 16 + 255) / 256;

    // ---- layer 1: res1 = relu(agg(BN1(x) @ W1) + b1)
    gemm_bn_kernel<128><<<gT, 256, 0, stream>>>(x, sc1, sh1, W1, T, N_NODES);
    self_init_kernel<128><<<g128, 256, 0, stream>>>(T, dinv, b1, res1, N_NODES);
    scatter_kernel<128><<<s128, 256, 0, stream>>>(T, dinv, ei, res1, N_EDGES);
    relu_kernel<<<g128, 256, 0, stream>>>(res1, N_NODES * 32);

    // ---- layer 2: res2 = relu(agg(BNm(res1) @ Wm) + bm)
    gemm_bn_kernel<128><<<gT, 256, 0, stream>>>(res1, scm, shm, Wm, T, N_NODES);
    self_init_kernel<128><<<g128, 256, 0, stream>>>(T, dinv, bm, res2, N_NODES);
    scatter_kernel<128><<<s128, 256, 0, stream>>>(T, dinv, ei, res2, N_EDGES);
    relu_kernel<<<g128, 256, 0, stream>>>(res2, N_NODES * 32);

    // ---- layer 3: out = agg(BN2(res2) @ W2) + b2   (no relu)
    gemm_bn_kernel<64><<<gT, 256, 0, stream>>>(res2, sc2, sh2, W2, T, N_NODES);
    self_init_kernel<64><<<g64, 256, 0, stream>>>(T, dinv, b2, out, N_NODES);
    scatter_kernel<64><<<s64, 256, 0, stream>>>(T, dinv, ei, out, N_EDGES);
}

// Round 2
// 372.304 us; speedup vs baseline: 7.9238x; 7.9238x over previous
//
#include <hip/hip_runtime.h>

#define N_NODES 100000
#define N_EDGES 640000
#define DIN 128
#define HDIM 128
#define DOUT 64

// ================= CSR build =================
__global__ void zero_cnt_kernel(int* cnt, int n) {
    int i = blockIdx.x * 256 + threadIdx.x;
    if (i < n) cnt[i] = 0;
}

__global__ void hist_kernel(const int* __restrict__ ei, int* cnt, int ne) {
    int e = blockIdx.x * 256 + threadIdx.x;
    if (e < ne) atomicAdd(&cnt[ei[ne + e]], 1);   // dst side
}

__global__ void dinv_kernel(const int* __restrict__ cnt, float* dinv, int n) {
    int i = blockIdx.x * 256 + threadIdx.x;
    if (i < n) dinv[i] = rsqrtf((float)cnt[i] + 1.0f);   // +1 self loop
}

// block-level exclusive scan (1024/block)
__global__ void scan_block_kernel(const int* __restrict__ cnt, int* __restrict__ off,
                                  int* __restrict__ bsums, int n) {
    __shared__ int sm[1024];
    int tid = threadIdx.x;
    int i = blockIdx.x * 1024 + tid;
    int v = (i < n) ? cnt[i] : 0;
    sm[tid] = v;
    __syncthreads();
    for (int d = 1; d < 1024; d <<= 1) {
        int t = (tid >= d) ? sm[tid - d] : 0;
        __syncthreads();
        sm[tid] += t;
        __syncthreads();
    }
    if (i < n) off[i] = sm[tid] - v;          // exclusive
    if (tid == 1023) bsums[blockIdx.x] = sm[1023];
}

__global__ void scan_bsums_kernel(int* bsums, int nb) {
    __shared__ int sm[128];
    int tid = threadIdx.x;
    int v = (tid < nb) ? bsums[tid] : 0;
    sm[tid] = v;
    __syncthreads();
    for (int d = 1; d < 128; d <<= 1) {
        int t = (tid >= d) ? sm[tid - d] : 0;
        __syncthreads();
        sm[tid] += t;
        __syncthreads();
    }
    if (tid < nb) bsums[tid] = sm[tid] - v;   // exclusive
}

__global__ void scan_add_kernel(int* __restrict__ off, int* __restrict__ cursor,
                                const int* __restrict__ bsums, int n) {
    int i = blockIdx.x * 256 + threadIdx.x;
    if (i < n) {
        int o = off[i] + bsums[i >> 10];
        off[i] = o;
        cursor[i] = o;
    }
}

__global__ void fill_csr_kernel(const int* __restrict__ ei, const float* __restrict__ dinv,
                                int* __restrict__ cursor, int* __restrict__ csr_src,
                                float* __restrict__ csr_coef, int ne) {
    int e = blockIdx.x * 256 + threadIdx.x;
    if (e < ne) {
        int s = ei[e], d = ei[ne + e];
        int pos = atomicAdd(&cursor[d], 1);
        csr_src[pos] = s;
        csr_coef[pos] = dinv[s] * dinv[d];
    }
}

// ================ BN fold ================
__global__ void bn_prep_kernel(const float* __restrict__ g, const float* __restrict__ b,
                               const float* __restrict__ m, const float* __restrict__ v,
                               float* __restrict__ scale, float* __restrict__ shift) {
    int i = threadIdx.x;  // 128 threads
    float s = g[i] * rsqrtf(v[i] + 1e-5f);
    scale[i] = s;
    shift[i] = b[i] - m[i] * s;
}

// ================ GEMM with BN folded into staging ================
// T[N][COUT] = (X*scale+shift) @ W
template<int COUT>
__global__ __launch_bounds__(256) void gemm_bn_kernel(
    const float* __restrict__ X, const float* __restrict__ scale,
    const float* __restrict__ shift, const float* __restrict__ W,
    float* __restrict__ T, int nrows)
{
    constexpr int CG  = COUT / 4;
    constexpr int RT  = 256 / CG;
    constexpr int RPT = 64 / RT;
    __shared__ float xs[64][132];

    int row0 = blockIdx.x * 64;
    int tid  = threadIdx.x;

    const float4* X4 = (const float4*)X;
    const float4* S4 = (const float4*)scale;
    const float4* H4 = (const float4*)shift;

    #pragma unroll
    for (int j = 0; j < 8; ++j) {
        int idx = tid + j * 256;
        int r = idx >> 5, c4 = idx & 31;
        int row = row0 + r;
        float4 v = make_float4(0.f, 0.f, 0.f, 0.f);
        if (row < nrows) v = X4[(size_t)row * 32 + c4];
        float4 s = S4[c4], h = H4[c4];
        xs[r][c4 * 4 + 0] = v.x * s.x + h.x;
        xs[r][c4 * 4 + 1] = v.y * s.y + h.y;
        xs[r][c4 * 4 + 2] = v.z * s.z + h.z;
        xs[r][c4 * 4 + 3] = v.w * s.w + h.w;
    }
    __syncthreads();

    int cg = tid % CG, rt = tid / CG;
    float acc[RPT][4];
    #pragma unroll
    for (int i = 0; i < RPT; ++i) {
        acc[i][0] = 0.f; acc[i][1] = 0.f; acc[i][2] = 0.f; acc[i][3] = 0.f;
    }

    const float4* W4 = (const float4*)W;
    for (int k = 0; k < 128; ++k) {
        float4 w = W4[k * CG + cg];
        #pragma unroll
        for (int i = 0; i < RPT; ++i) {
            float xv = xs[rt + i * RT][k];
            acc[i][0] += xv * w.x;
            acc[i][1] += xv * w.y;
            acc[i][2] += xv * w.z;
            acc[i][3] += xv * w.w;
        }
    }

    float4* T4 = (float4*)T;
    #pragma unroll
    for (int i = 0; i < RPT; ++i) {
        int row = row0 + rt + i * RT;
        if (row < nrows) {
            float4 o;
            o.x = acc[i][0]; o.y = acc[i][1]; o.z = acc[i][2]; o.w = acc[i][3];
            T4[(size_t)row * CG + cg] = o;
        }
    }
}

// ================ fused gather: out = [relu](sum_in T[s]*coef + T[i]*dinv^2 + bias) ================
template<int COUT, bool RELU>
__global__ __launch_bounds__(256) void gather_kernel(
    const float* __restrict__ T, const float* __restrict__ dinv,
    const int* __restrict__ off, const int* __restrict__ cnt,
    const int* __restrict__ csr_src, const float* __restrict__ csr_coef,
    const float* __restrict__ bias, float* __restrict__ out, int n)
{
    constexpr int CG = COUT / 4;   // lanes per node
    int tid  = blockIdx.x * 256 + threadIdx.x;
    int node = tid / CG, c = tid % CG;
    if (node >= n) return;

    const float4* T4 = (const float4*)T;
    float di   = dinv[node];
    float cf0  = di * di;
    float4 acc = T4[(size_t)node * CG + c];
    float4 b   = ((const float4*)bias)[c];
    acc.x = acc.x * cf0 + b.x;
    acc.y = acc.y * cf0 + b.y;
    acc.z = acc.z * cf0 + b.z;
    acc.w = acc.w * cf0 + b.w;

    int st = off[node];
    int en = st + cnt[node];
    int e  = st;
    for (; e + 1 < en; e += 2) {
        int   s0 = csr_src[e],     s1 = csr_src[e + 1];
        float c0 = csr_coef[e],    c1 = csr_coef[e + 1];
        float4 v0 = T4[(size_t)s0 * CG + c];
        float4 v1 = T4[(size_t)s1 * CG + c];
        acc.x += v0.x * c0 + v1.x * c1;
        acc.y += v0.y * c0 + v1.y * c1;
        acc.z += v0.z * c0 + v1.z * c1;
        acc.w += v0.w * c0 + v1.w * c1;
    }
    if (e < en) {
        int   s0 = csr_src[e];
        float c0 = csr_coef[e];
        float4 v0 = T4[(size_t)s0 * CG + c];
        acc.x += v0.x * c0;
        acc.y += v0.y * c0;
        acc.z += v0.z * c0;
        acc.w += v0.w * c0;
    }

    if (RELU) {
        acc.x = fmaxf(acc.x, 0.f);
        acc.y = fmaxf(acc.y, 0.f);
        acc.z = fmaxf(acc.z, 0.f);
        acc.w = fmaxf(acc.w, 0.f);
    }
    ((float4*)out)[(size_t)node * CG + c] = acc;
}

extern "C" void kernel_launch(void* const* d_in, const int* in_sizes, int n_in,
                              void* d_out, int out_size, void* d_ws, size_t ws_size,
                              hipStream_t stream) {
    const float* x   = (const float*)d_in[0];
    const int*   ei  = (const int*)d_in[1];
    const float* W1  = (const float*)d_in[4];
    const float* b1  = (const float*)d_in[5];
    const float* Wm  = (const float*)d_in[6];
    const float* bm  = (const float*)d_in[7];
    const float* W2  = (const float*)d_in[8];
    const float* b2  = (const float*)d_in[9];
    const float* bn1g = (const float*)d_in[10];
    const float* bn1b = (const float*)d_in[11];
    const float* bn1m = (const float*)d_in[12];
    const float* bn1v = (const float*)d_in[13];
    const float* bnmg = (const float*)d_in[14];
    const float* bnmb = (const float*)d_in[15];
    const float* bnmm = (const float*)d_in[16];
    const float* bnmv = (const float*)d_in[17];
    const float* bn2g = (const float*)d_in[18];
    const float* bn2b = (const float*)d_in[19];
    const float* bn2m = (const float*)d_in[20];
    const float* bn2v = (const float*)d_in[21];

    float* out  = (float*)d_out;
    float* res1 = out + (size_t)N_NODES * DOUT;
    float* res2 = res1 + (size_t)N_NODES * HDIM;

    // workspace layout
    float* T    = (float*)d_ws;                       // N*128 floats
    float* dinv = T + (size_t)N_NODES * HDIM;         // N
    float* sc1  = dinv + N_NODES;
    float* sh1  = sc1 + 128;
    float* scm  = sh1 + 128;
    float* shm  = scm + 128;
    float* sc2  = shm + 128;
    float* sh2  = sc2 + 128;
    int*   cnt     = (int*)(sh2 + 128);               // N
    int*   off     = cnt + N_NODES;                   // N
    int*   cursor  = off + N_NODES;                   // N
    int*   bsums   = cursor + N_NODES;                // 128
    int*   csr_src = bsums + 128;                     // E
    float* csr_coef= (float*)(csr_src + N_EDGES);     // E

    int gN = (N_NODES + 255) / 256;
    int gE = (N_EDGES + 255) / 256;
    int gT = (N_NODES + 63) / 64;
    int nb = (N_NODES + 1023) / 1024;                 // 98 scan blocks

    // ---- CSR build + dinv
    zero_cnt_kernel<<<gN, 256, 0, stream>>>(cnt, N_NODES);
    hist_kernel<<<gE, 256, 0, stream>>>(ei, cnt, N_EDGES);
    dinv_kernel<<<gN, 256, 0, stream>>>(cnt, dinv, N_NODES);
    scan_block_kernel<<<nb, 1024, 0, stream>>>(cnt, off, bsums, N_NODES);
    scan_bsums_kernel<<<1, 128, 0, stream>>>(bsums, nb);
    scan_add_kernel<<<gN, 256, 0, stream>>>(off, cursor, bsums, N_NODES);
    fill_csr_kernel<<<gE, 256, 0, stream>>>(ei, dinv, cursor, csr_src, csr_coef, N_EDGES);

    // ---- BN folds
    bn_prep_kernel<<<1, 128, 0, stream>>>(bn1g, bn1b, bn1m, bn1v, sc1, sh1);
    bn_prep_kernel<<<1, 128, 0, stream>>>(bnmg, bnmb, bnmm, bnmv, scm, shm);
    bn_prep_kernel<<<1, 128, 0, stream>>>(bn2g, bn2b, bn2m, bn2v, sc2, sh2);

    int gG128 = (N_NODES * 32 + 255) / 256;   // gather grid, COUT=128
    int gG64  = (N_NODES * 16 + 255) / 256;   // gather grid, COUT=64

    // ---- layer 1: res1 = relu(agg(BN1(x) @ W1) + b1)
    gemm_bn_kernel<128><<<gT, 256, 0, stream>>>(x, sc1, sh1, W1, T, N_NODES);
    gather_kernel<128, true><<<gG128, 256, 0, stream>>>(T, dinv, off, cnt, csr_src, csr_coef, b1, res1, N_NODES);

    // ---- layer 2: res2 = relu(agg(BNm(res1) @ Wm) + bm)
    gemm_bn_kernel<128><<<gT, 256, 0, stream>>>(res1, scm, shm, Wm, T, N_NODES);
    gather_kernel<128, true><<<gG128, 256, 0, stream>>>(T, dinv, off, cnt, csr_src, csr_coef, bm, res2, N_NODES);

    // ---- layer 3: out = agg(BN2(res2) @ W2) + b2
    gemm_bn_kernel<64><<<gT, 256, 0, stream>>>(res2, sc2, sh2, W2, T, N_NODES);
    gather_kernel<64, false><<<gG64, 256, 0, stream>>>(T, dinv, off, cnt, csr_src, csr_coef, b2, out, N_NODES);
}

// Round 3
// 322.075 us; speedup vs baseline: 9.1596x; 1.1560x over previous
//
#include <hip/hip_runtime.h>

#define N_NODES 100000
#define N_EDGES 640000
#define DIN 128
#define HDIM 128
#define DOUT 64

// ---------- bf16 helpers ----------
__device__ inline unsigned short f2bf(float x) {
    unsigned u = __float_as_uint(x);
    unsigned r = (u + 0x7fffu + ((u >> 16) & 1u)) >> 16;   // RNE
    return (unsigned short)r;
}
__device__ inline void unpack2(unsigned u, float& f0, float& f1) {
    f0 = __uint_as_float(u << 16);
    f1 = __uint_as_float(u & 0xffff0000u);
}

// ================= CSR build =================
__global__ void zero_cnt_kernel(int* cnt, int n) {
    int i = blockIdx.x * 256 + threadIdx.x;
    if (i < n) cnt[i] = 0;
}

__global__ void hist_kernel(const int* __restrict__ ei, int* cnt, int ne) {
    int e = blockIdx.x * 256 + threadIdx.x;
    if (e < ne) atomicAdd(&cnt[ei[ne + e]], 1);   // dst side
}

// block-level exclusive scan (1024/block)
__global__ void scan_block_kernel(const int* __restrict__ cnt, int* __restrict__ off,
                                  int* __restrict__ bsums, int n) {
    __shared__ int sm[1024];
    int tid = threadIdx.x;
    int i = blockIdx.x * 1024 + tid;
    int v = (i < n) ? cnt[i] : 0;
    sm[tid] = v;
    __syncthreads();
    for (int d = 1; d < 1024; d <<= 1) {
        int t = (tid >= d) ? sm[tid - d] : 0;
        __syncthreads();
        sm[tid] += t;
        __syncthreads();
    }
    if (i < n) off[i] = sm[tid] - v;          // exclusive
    if (tid == 1023) bsums[blockIdx.x] = sm[1023];
}

__global__ void scan_bsums_kernel(int* bsums, int nb) {
    __shared__ int sm[128];
    int tid = threadIdx.x;
    int v = (tid < nb) ? bsums[tid] : 0;
    sm[tid] = v;
    __syncthreads();
    for (int d = 1; d < 128; d <<= 1) {
        int t = (tid >= d) ? sm[tid - d] : 0;
        __syncthreads();
        sm[tid] += t;
        __syncthreads();
    }
    if (tid < nb) bsums[tid] = sm[tid] - v;   // exclusive
}

// scan finalize + cursor init + dinv
__global__ void scan_add_kernel(int* __restrict__ off, int* __restrict__ cursor,
                                const int* __restrict__ bsums, const int* __restrict__ cnt,
                                float* __restrict__ dinv, int n) {
    int i = blockIdx.x * 256 + threadIdx.x;
    if (i < n) {
        int o = off[i] + bsums[i >> 10];
        off[i] = o;
        cursor[i] = o;
        dinv[i] = rsqrtf((float)cnt[i] + 1.0f);   // +1 self loop
    }
}

__global__ void fill_csr_kernel(const int* __restrict__ ei, const float* __restrict__ dinv,
                                int* __restrict__ cursor, int* __restrict__ csr_src,
                                float* __restrict__ csr_coef, int ne) {
    int e = blockIdx.x * 256 + threadIdx.x;
    if (e < ne) {
        int s = ei[e], d = ei[ne + e];
        int pos = atomicAdd(&cursor[d], 1);
        csr_src[pos] = s;
        csr_coef[pos] = dinv[s] * dinv[d];
    }
}

// ================ BN fold ================
__global__ void bn_prep_kernel(const float* __restrict__ g, const float* __restrict__ b,
                               const float* __restrict__ m, const float* __restrict__ v,
                               float* __restrict__ scale, float* __restrict__ shift) {
    int i = threadIdx.x;  // 128 threads
    float s = g[i] * rsqrtf(v[i] + 1e-5f);
    scale[i] = s;
    shift[i] = b[i] - m[i] * s;
}

// ================ GEMM with BN folded, bf16 output ================
// T[N][COUT] (bf16) = (X*scale+shift) @ W
template<int COUT>
__global__ __launch_bounds__(256) void gemm_bn_kernel(
    const float* __restrict__ X, const float* __restrict__ scale,
    const float* __restrict__ shift, const float* __restrict__ W,
    unsigned short* __restrict__ T, int nrows)
{
    constexpr int CG  = COUT / 4;
    constexpr int RT  = 256 / CG;
    constexpr int RPT = 64 / RT;
    __shared__ float xs[64][132];

    int row0 = blockIdx.x * 64;
    int tid  = threadIdx.x;

    const float4* X4 = (const float4*)X;
    const float4* S4 = (const float4*)scale;
    const float4* H4 = (const float4*)shift;

    #pragma unroll
    for (int j = 0; j < 8; ++j) {
        int idx = tid + j * 256;
        int r = idx >> 5, c4 = idx & 31;
        int row = row0 + r;
        float4 v = make_float4(0.f, 0.f, 0.f, 0.f);
        if (row < nrows) v = X4[(size_t)row * 32 + c4];
        float4 s = S4[c4], h = H4[c4];
        xs[r][c4 * 4 + 0] = v.x * s.x + h.x;
        xs[r][c4 * 4 + 1] = v.y * s.y + h.y;
        xs[r][c4 * 4 + 2] = v.z * s.z + h.z;
        xs[r][c4 * 4 + 3] = v.w * s.w + h.w;
    }
    __syncthreads();

    int cg = tid % CG, rt = tid / CG;
    float acc[RPT][4];
    #pragma unroll
    for (int i = 0; i < RPT; ++i) {
        acc[i][0] = 0.f; acc[i][1] = 0.f; acc[i][2] = 0.f; acc[i][3] = 0.f;
    }

    const float4* W4 = (const float4*)W;
    for (int k = 0; k < 128; ++k) {
        float4 w = W4[k * CG + cg];
        #pragma unroll
        for (int i = 0; i < RPT; ++i) {
            float xv = xs[rt + i * RT][k];
            acc[i][0] += xv * w.x;
            acc[i][1] += xv * w.y;
            acc[i][2] += xv * w.z;
            acc[i][3] += xv * w.w;
        }
    }

    #pragma unroll
    for (int i = 0; i < RPT; ++i) {
        int row = row0 + rt + i * RT;
        if (row < nrows) {
            ushort4 o;
            o.x = f2bf(acc[i][0]); o.y = f2bf(acc[i][1]);
            o.z = f2bf(acc[i][2]); o.w = f2bf(acc[i][3]);
            ((ushort4*)T)[(size_t)row * CG + cg] = o;
        }
    }
}

// ===== fused gather (bf16 T): out = [relu](sum_in T[s]*coef + T[i]*dinv^2 + bias) =====
template<int COUT, bool RELU>
__global__ __launch_bounds__(256) void gather_kernel(
    const unsigned short* __restrict__ T, const float* __restrict__ dinv,
    const int* __restrict__ off, const int* __restrict__ cnt,
    const int* __restrict__ csr_src, const float* __restrict__ csr_coef,
    const float* __restrict__ bias, float* __restrict__ out, int n)
{
    constexpr int LPN = COUT / 8;   // lanes per node, 16B (8 bf16) each
    int tid  = blockIdx.x * 256 + threadIdx.x;
    int node = tid / LPN, lane = tid % LPN;
    if (node >= n) return;

    const uint4* T4 = (const uint4*)T;   // 8 bf16 per uint4
    float di  = dinv[node];
    float cf0 = di * di;

    float acc[8];
    {
        uint4 tv = T4[(size_t)node * LPN + lane];
        float f[8];
        unpack2(tv.x, f[0], f[1]); unpack2(tv.y, f[2], f[3]);
        unpack2(tv.z, f[4], f[5]); unpack2(tv.w, f[6], f[7]);
        float4 b0 = ((const float4*)bias)[lane * 2];
        float4 b1 = ((const float4*)bias)[lane * 2 + 1];
        acc[0] = f[0] * cf0 + b0.x; acc[1] = f[1] * cf0 + b0.y;
        acc[2] = f[2] * cf0 + b0.z; acc[3] = f[3] * cf0 + b0.w;
        acc[4] = f[4] * cf0 + b1.x; acc[5] = f[5] * cf0 + b1.y;
        acc[6] = f[6] * cf0 + b1.z; acc[7] = f[7] * cf0 + b1.w;
    }

    int st = off[node];
    int en = st + cnt[node];
    int e  = st;
    for (; e + 1 < en; e += 2) {
        int   s0 = csr_src[e],   s1 = csr_src[e + 1];
        float c0 = csr_coef[e],  c1 = csr_coef[e + 1];
        uint4 v0 = T4[(size_t)s0 * LPN + lane];
        uint4 v1 = T4[(size_t)s1 * LPN + lane];
        float f0[8], f1[8];
        unpack2(v0.x, f0[0], f0[1]); unpack2(v0.y, f0[2], f0[3]);
        unpack2(v0.z, f0[4], f0[5]); unpack2(v0.w, f0[6], f0[7]);
        unpack2(v1.x, f1[0], f1[1]); unpack2(v1.y, f1[2], f1[3]);
        unpack2(v1.z, f1[4], f1[5]); unpack2(v1.w, f1[6], f1[7]);
        #pragma unroll
        for (int j = 0; j < 8; ++j) acc[j] += f0[j] * c0 + f1[j] * c1;
    }
    if (e < en) {
        int   s0 = csr_src[e];
        float c0 = csr_coef[e];
        uint4 v0 = T4[(size_t)s0 * LPN + lane];
        float f0[8];
        unpack2(v0.x, f0[0], f0[1]); unpack2(v0.y, f0[2], f0[3]);
        unpack2(v0.z, f0[4], f0[5]); unpack2(v0.w, f0[6], f0[7]);
        #pragma unroll
        for (int j = 0; j < 8; ++j) acc[j] += f0[j] * c0;
    }

    if (RELU) {
        #pragma unroll
        for (int j = 0; j < 8; ++j) acc[j] = fmaxf(acc[j], 0.f);
    }
    float4* O4 = (float4*)out;
    float4 o0, o1;
    o0.x = acc[0]; o0.y = acc[1]; o0.z = acc[2]; o0.w = acc[3];
    o1.x = acc[4]; o1.y = acc[5]; o1.z = acc[6]; o1.w = acc[7];
    O4[(size_t)node * LPN * 2 + lane * 2]     = o0;
    O4[(size_t)node * LPN * 2 + lane * 2 + 1] = o1;
}

extern "C" void kernel_launch(void* const* d_in, const int* in_sizes, int n_in,
                              void* d_out, int out_size, void* d_ws, size_t ws_size,
                              hipStream_t stream) {
    const float* x   = (const float*)d_in[0];
    const int*   ei  = (const int*)d_in[1];
    const float* W1  = (const float*)d_in[4];
    const float* b1  = (const float*)d_in[5];
    const float* Wm  = (const float*)d_in[6];
    const float* bm  = (const float*)d_in[7];
    const float* W2  = (const float*)d_in[8];
    const float* b2  = (const float*)d_in[9];
    const float* bn1g = (const float*)d_in[10];
    const float* bn1b = (const float*)d_in[11];
    const float* bn1m = (const float*)d_in[12];
    const float* bn1v = (const float*)d_in[13];
    const float* bnmg = (const float*)d_in[14];
    const float* bnmb = (const float*)d_in[15];
    const float* bnmm = (const float*)d_in[16];
    const float* bnmv = (const float*)d_in[17];
    const float* bn2g = (const float*)d_in[18];
    const float* bn2b = (const float*)d_in[19];
    const float* bn2m = (const float*)d_in[20];
    const float* bn2v = (const float*)d_in[21];

    float* out  = (float*)d_out;
    float* res1 = out + (size_t)N_NODES * DOUT;
    float* res2 = res1 + (size_t)N_NODES * HDIM;

    // workspace layout
    unsigned short* T = (unsigned short*)d_ws;              // N*128 bf16 (25.6 MB)
    float* dinv = (float*)(T + (size_t)N_NODES * HDIM);     // N
    float* sc1  = dinv + N_NODES;
    float* sh1  = sc1 + 128;
    float* scm  = sh1 + 128;
    float* shm  = scm + 128;
    float* sc2  = shm + 128;
    float* sh2  = sc2 + 128;
    int*   cnt     = (int*)(sh2 + 128);               // N
    int*   off     = cnt + N_NODES;                   // N
    int*   cursor  = off + N_NODES;                   // N
    int*   bsums   = cursor + N_NODES;                // 128
    int*   csr_src = bsums + 128;                     // E
    float* csr_coef= (float*)(csr_src + N_EDGES);     // E

    int gN = (N_NODES + 255) / 256;
    int gE = (N_EDGES + 255) / 256;
    int gT = (N_NODES + 63) / 64;
    int nb = (N_NODES + 1023) / 1024;                 // 98 scan blocks

    // ---- CSR build + dinv
    zero_cnt_kernel<<<gN, 256, 0, stream>>>(cnt, N_NODES);
    hist_kernel<<<gE, 256, 0, stream>>>(ei, cnt, N_EDGES);
    scan_block_kernel<<<nb, 1024, 0, stream>>>(cnt, off, bsums, N_NODES);
    scan_bsums_kernel<<<1, 128, 0, stream>>>(bsums, nb);
    scan_add_kernel<<<gN, 256, 0, stream>>>(off, cursor, bsums, cnt, dinv, N_NODES);
    fill_csr_kernel<<<gE, 256, 0, stream>>>(ei, dinv, cursor, csr_src, csr_coef, N_EDGES);

    // ---- BN folds
    bn_prep_kernel<<<1, 128, 0, stream>>>(bn1g, bn1b, bn1m, bn1v, sc1, sh1);
    bn_prep_kernel<<<1, 128, 0, stream>>>(bnmg, bnmb, bnmm, bnmv, scm, shm);
    bn_prep_kernel<<<1, 128, 0, stream>>>(bn2g, bn2b, bn2m, bn2v, sc2, sh2);

    int gG128 = (N_NODES * 16 + 255) / 256;   // gather grid, COUT=128 (16 lanes/node)
    int gG64  = (N_NODES * 8 + 255) / 256;    // gather grid, COUT=64  (8 lanes/node)

    // ---- layer 1: res1 = relu(agg(BN1(x) @ W1) + b1)
    gemm_bn_kernel<128><<<gT, 256, 0, stream>>>(x, sc1, sh1, W1, T, N_NODES);
    gather_kernel<128, true><<<gG128, 256, 0, stream>>>(T, dinv, off, cnt, csr_src, csr_coef, b1, res1, N_NODES);

    // ---- layer 2: res2 = relu(agg(BNm(res1) @ Wm) + bm)
    gemm_bn_kernel<128><<<gT, 256, 0, stream>>>(res1, scm, shm, Wm, T, N_NODES);
    gather_kernel<128, true><<<gG128, 256, 0, stream>>>(T, dinv, off, cnt, csr_src, csr_coef, bm, res2, N_NODES);

    // ---- layer 3: out = agg(BN2(res2) @ W2) + b2
    gemm_bn_kernel<64><<<gT, 256, 0, stream>>>(res2, sc2, sh2, W2, T, N_NODES);
    gather_kernel<64, false><<<gG64, 256, 0, stream>>>(T, dinv, off, cnt, csr_src, csr_coef, b2, out, N_NODES);
}

// Round 4
// 256.281 us; speedup vs baseline: 11.5111x; 1.2567x over previous
//
#include <hip/hip_runtime.h>

#define N_NODES 100000
#define N_EDGES 640000
#define DIN 128
#define HDIM 128
#define DOUT 64

typedef __attribute__((ext_vector_type(4))) float f32x4;
typedef __attribute__((ext_vector_type(8))) short bf16x8;

// ---------- bf16 helpers ----------
__device__ inline unsigned short f2bf(float x) {
    unsigned u = __float_as_uint(x);
    unsigned r = (u + 0x7fffu + ((u >> 16) & 1u)) >> 16;   // RNE
    return (unsigned short)r;
}
__device__ inline void unpack2(unsigned u, float& f0, float& f1) {
    f0 = __uint_as_float(u << 16);
    f1 = __uint_as_float(u & 0xffff0000u);
}

// ================= CSR build =================
__global__ void hist_kernel(const int* __restrict__ ei, int* cnt, int ne) {
    int e = blockIdx.x * 256 + threadIdx.x;
    if (e < ne) atomicAdd(&cnt[ei[ne + e]], 1);   // dst side
}

__global__ void scan_block_kernel(const int* __restrict__ cnt, int* __restrict__ off,
                                  int* __restrict__ bsums, int n) {
    __shared__ int sm[1024];
    int tid = threadIdx.x;
    int i = blockIdx.x * 1024 + tid;
    int v = (i < n) ? cnt[i] : 0;
    sm[tid] = v;
    __syncthreads();
    for (int d = 1; d < 1024; d <<= 1) {
        int t = (tid >= d) ? sm[tid - d] : 0;
        __syncthreads();
        sm[tid] += t;
        __syncthreads();
    }
    if (i < n) off[i] = sm[tid] - v;          // exclusive
    if (tid == 1023) bsums[blockIdx.x] = sm[1023];
}

__global__ void scan_bsums_kernel(int* bsums, int nb) {
    __shared__ int sm[128];
    int tid = threadIdx.x;
    int v = (tid < nb) ? bsums[tid] : 0;
    sm[tid] = v;
    __syncthreads();
    for (int d = 1; d < 128; d <<= 1) {
        int t = (tid >= d) ? sm[tid - d] : 0;
        __syncthreads();
        sm[tid] += t;
        __syncthreads();
    }
    if (tid < nb) bsums[tid] = sm[tid] - v;   // exclusive
}

__global__ void scan_add_kernel(int* __restrict__ off, int* __restrict__ cursor,
                                const int* __restrict__ bsums, const int* __restrict__ cnt,
                                float* __restrict__ dinv, int n) {
    int i = blockIdx.x * 256 + threadIdx.x;
    if (i < n) {
        int o = off[i] + bsums[i >> 10];
        off[i] = o;
        cursor[i] = o;
        dinv[i] = rsqrtf((float)cnt[i] + 1.0f);   // +1 self loop
    }
}

__global__ void fill_csr_kernel(const int* __restrict__ ei, const float* __restrict__ dinv,
                                int* __restrict__ cursor, int* __restrict__ csr_src,
                                float* __restrict__ csr_coef, int ne) {
    int e = blockIdx.x * 256 + threadIdx.x;
    if (e < ne) {
        int s = ei[e], d = ei[ne + e];
        int pos = atomicAdd(&cursor[d], 1);
        csr_src[pos] = s;
        csr_coef[pos] = dinv[s] * dinv[d];
    }
}

// ================ prep: BN fold + weight transform ================
struct PrepPtrs {
    const float *g[3], *b[3], *m[3], *v[3];   // BN params per layer
    const float *W[3];                         // weights f32 [128][COUT]
    float *sc[3], *sh[3], *tW[3];              // outputs
    unsigned short *wt[3];                     // bf16 [COUT][128]
};

// scale/shift, 3 layers in one launch (blockIdx.x = layer, 128 threads)
__global__ void bn_prep_all_kernel(PrepPtrs p) {
    int l = blockIdx.x, i = threadIdx.x;
    float s = p.g[l][i] * rsqrtf(p.v[l][i] + 1e-5f);
    p.sc[l][i] = s;
    p.sh[l][i] = p.b[l][i] - p.m[l][i] * s;
}

// wt[l][c][k] = bf16(W[l][k][c] * sc[l][k]); grid.y = layer
__global__ void wprep_all_kernel(PrepPtrs p) {
    int l = blockIdx.y;
    int cout = (l == 2) ? DOUT : HDIM;
    int idx = blockIdx.x * 256 + threadIdx.x;   // k*cout + c (read-coalesced)
    if (idx >= 128 * cout) return;
    int k = idx / cout, c = idx % cout;
    p.wt[l][c * 128 + k] = f2bf(p.W[l][idx] * p.sc[l][k]);
}

// tW[l][c] = sum_k sh[l][k] * W[l][k][c]; blockIdx.x = layer, 128 threads
__global__ void tw_all_kernel(PrepPtrs p) {
    int l = blockIdx.x, c = threadIdx.x;
    int cout = (l == 2) ? DOUT : HDIM;
    if (c >= cout) return;
    float acc = 0.f;
    for (int k = 0; k < 128; ++k) acc += p.sh[l][k] * p.W[l][k * cout + c];
    p.tW[l][c] = acc;
}

// ================ MFMA bf16 GEMM ================
// T[N][COUT] (bf16) = bf16(X) @ wt^T + tW    (BN folded into wt/tW)
template<int COUT>
__global__ __launch_bounds__(256) void gemm_mfma_kernel(
    const float* __restrict__ X, const unsigned short* __restrict__ Wt,
    const float* __restrict__ tW, unsigned short* __restrict__ T, int nrows)
{
    constexpr int LDT = 136;                         // padded row (bf16 units), 272B
    __shared__ unsigned short xs[64 * LDT];          // 17408 B
    __shared__ unsigned short ws[COUT * LDT];        // 34816 B (COUT=128)

    int tid  = threadIdx.x;
    int wave = tid >> 6, lane = tid & 63;
    int row0 = blockIdx.x * 64;

    // stage Wt (bf16 [COUT][128]) into padded LDS
    {
        const uint4* src = (const uint4*)Wt;         // 8 bf16 per uint4, 16/row
        #pragma unroll
        for (int it = 0; it < COUT / 16; ++it) {
            int idx = tid + it * 256;
            int r = idx >> 4, c8 = idx & 15;
            uint4 v = src[idx];
            *(uint4*)&ws[r * LDT + c8 * 8] = v;
        }
    }
    // stage X tile: f32 -> bf16
    {
        const float4* X4 = (const float4*)X;
        #pragma unroll
        for (int it = 0; it < 8; ++it) {
            int idx = tid + it * 256;
            int r = idx >> 5, c4 = idx & 31;
            int row = row0 + r;
            float4 v = make_float4(0.f, 0.f, 0.f, 0.f);
            if (row < nrows) v = X4[(size_t)row * 32 + c4];
            ushort4 o;
            o.x = f2bf(v.x); o.y = f2bf(v.y); o.z = f2bf(v.z); o.w = f2bf(v.w);
            *(ushort4*)&xs[r * LDT + c4 * 4] = o;
        }
    }
    __syncthreads();

    constexpr int NT = COUT / 16;                    // col tiles per wave
    f32x4 acc[NT];
    #pragma unroll
    for (int t = 0; t < NT; ++t) acc[t] = (f32x4)(0.f);

    int arow = wave * 16 + (lane & 15);
    int khi  = (lane >> 4) * 8;

    #pragma unroll
    for (int kk = 0; kk < 4; ++kk) {
        bf16x8 a = *(const bf16x8*)&xs[arow * LDT + kk * 32 + khi];
        #pragma unroll
        for (int t = 0; t < NT; ++t) {
            bf16x8 b = *(const bf16x8*)&ws[(t * 16 + (lane & 15)) * LDT + kk * 32 + khi];
            acc[t] = __builtin_amdgcn_mfma_f32_16x16x32_bf16(a, b, acc[t], 0, 0, 0);
        }
    }

    // epilogue: C row=(lane>>4)*4+r, col=lane&15 within each 16x16 tile
    int crow0 = (lane >> 4) * 4;
    int ccol  = lane & 15;
    #pragma unroll
    for (int t = 0; t < NT; ++t) {
        int col = t * 16 + ccol;
        float tw = tW[col];
        #pragma unroll
        for (int r = 0; r < 4; ++r) {
            int row = row0 + wave * 16 + crow0 + r;
            if (row < nrows)
                T[(size_t)row * COUT + col] = f2bf(acc[t][r] + tw);
        }
    }
}

// ===== fused gather (bf16 T): out = [relu](sum_in T[s]*coef + T[i]*dinv^2 + bias) =====
template<int COUT, bool RELU>
__global__ __launch_bounds__(256) void gather_kernel(
    const unsigned short* __restrict__ T, const float* __restrict__ dinv,
    const int* __restrict__ off, const int* __restrict__ cnt,
    const int* __restrict__ csr_src, const float* __restrict__ csr_coef,
    const float* __restrict__ bias, float* __restrict__ out, int n)
{
    constexpr int LPN = COUT / 8;   // lanes per node, 16B (8 bf16) each
    int tid  = blockIdx.x * 256 + threadIdx.x;
    int node = tid / LPN, lane = tid % LPN;
    if (node >= n) return;

    const uint4* T4 = (const uint4*)T;
    float di  = dinv[node];
    float cf0 = di * di;

    float acc[8];
    {
        uint4 tv = T4[(size_t)node * LPN + lane];
        float f[8];
        unpack2(tv.x, f[0], f[1]); unpack2(tv.y, f[2], f[3]);
        unpack2(tv.z, f[4], f[5]); unpack2(tv.w, f[6], f[7]);
        float4 b0 = ((const float4*)bias)[lane * 2];
        float4 b1 = ((const float4*)bias)[lane * 2 + 1];
        acc[0] = f[0] * cf0 + b0.x; acc[1] = f[1] * cf0 + b0.y;
        acc[2] = f[2] * cf0 + b0.z; acc[3] = f[3] * cf0 + b0.w;
        acc[4] = f[4] * cf0 + b1.x; acc[5] = f[5] * cf0 + b1.y;
        acc[6] = f[6] * cf0 + b1.z; acc[7] = f[7] * cf0 + b1.w;
    }

    int st = off[node];
    int en = st + cnt[node];
    int e  = st;
    for (; e + 1 < en; e += 2) {
        int   s0 = csr_src[e],   s1 = csr_src[e + 1];
        float c0 = csr_coef[e],  c1 = csr_coef[e + 1];
        uint4 v0 = T4[(size_t)s0 * LPN + lane];
        uint4 v1 = T4[(size_t)s1 * LPN + lane];
        float f0[8], f1[8];
        unpack2(v0.x, f0[0], f0[1]); unpack2(v0.y, f0[2], f0[3]);
        unpack2(v0.z, f0[4], f0[5]); unpack2(v0.w, f0[6], f0[7]);
        unpack2(v1.x, f1[0], f1[1]); unpack2(v1.y, f1[2], f1[3]);
        unpack2(v1.z, f1[4], f1[5]); unpack2(v1.w, f1[6], f1[7]);
        #pragma unroll
        for (int j = 0; j < 8; ++j) acc[j] += f0[j] * c0 + f1[j] * c1;
    }
    if (e < en) {
        int   s0 = csr_src[e];
        float c0 = csr_coef[e];
        uint4 v0 = T4[(size_t)s0 * LPN + lane];
        float f0[8];
        unpack2(v0.x, f0[0], f0[1]); unpack2(v0.y, f0[2], f0[3]);
        unpack2(v0.z, f0[4], f0[5]); unpack2(v0.w, f0[6], f0[7]);
        #pragma unroll
        for (int j = 0; j < 8; ++j) acc[j] += f0[j] * c0;
    }

    if (RELU) {
        #pragma unroll
        for (int j = 0; j < 8; ++j) acc[j] = fmaxf(acc[j], 0.f);
    }
    float4* O4 = (float4*)out;
    float4 o0, o1;
    o0.x = acc[0]; o0.y = acc[1]; o0.z = acc[2]; o0.w = acc[3];
    o1.x = acc[4]; o1.y = acc[5]; o1.z = acc[6]; o1.w = acc[7];
    O4[(size_t)node * LPN * 2 + lane * 2]     = o0;
    O4[(size_t)node * LPN * 2 + lane * 2 + 1] = o1;
}

extern "C" void kernel_launch(void* const* d_in, const int* in_sizes, int n_in,
                              void* d_out, int out_size, void* d_ws, size_t ws_size,
                              hipStream_t stream) {
    const float* x   = (const float*)d_in[0];
    const int*   ei  = (const int*)d_in[1];
    const float* W1  = (const float*)d_in[4];
    const float* b1  = (const float*)d_in[5];
    const float* Wm  = (const float*)d_in[6];
    const float* bm  = (const float*)d_in[7];
    const float* W2  = (const float*)d_in[8];
    const float* b2  = (const float*)d_in[9];

    float* out  = (float*)d_out;
    float* res1 = out + (size_t)N_NODES * DOUT;
    float* res2 = res1 + (size_t)N_NODES * HDIM;

    // ---- workspace layout (16B-aligned chunks first) ----
    unsigned short* T   = (unsigned short*)d_ws;            // N*128 bf16
    unsigned short* wt1 = T + (size_t)N_NODES * HDIM;       // 128*128
    unsigned short* wtm = wt1 + 128 * HDIM;                 // 128*128
    unsigned short* wt2 = wtm + 128 * HDIM;                 // 64*128
    float* dinv = (float*)(wt2 + DOUT * 128);               // N
    float* sc1  = dinv + N_NODES;
    float* sh1  = sc1 + 128;
    float* scm  = sh1 + 128;
    float* shm  = scm + 128;
    float* sc2  = shm + 128;
    float* sh2  = sc2 + 128;
    float* tW1  = sh2 + 128;
    float* tWm  = tW1 + 128;
    float* tW2  = tWm + 128;
    int*   cnt     = (int*)(tW2 + 64);                // N
    int*   off     = cnt + N_NODES;                   // N
    int*   cursor  = off + N_NODES;                   // N
    int*   bsums   = cursor + N_NODES;                // 128
    int*   csr_src = bsums + 128;                     // E
    float* csr_coef= (float*)(csr_src + N_EDGES);     // E

    int gN = (N_NODES + 255) / 256;
    int gE = (N_EDGES + 255) / 256;
    int gT = (N_NODES + 63) / 64;
    int nb = (N_NODES + 1023) / 1024;                 // 98 scan blocks

    // ---- CSR build + dinv
    hipMemsetAsync(cnt, 0, N_NODES * sizeof(int), stream);
    hist_kernel<<<gE, 256, 0, stream>>>(ei, cnt, N_EDGES);
    scan_block_kernel<<<nb, 1024, 0, stream>>>(cnt, off, bsums, N_NODES);
    scan_bsums_kernel<<<1, 128, 0, stream>>>(bsums, nb);
    scan_add_kernel<<<gN, 256, 0, stream>>>(off, cursor, bsums, cnt, dinv, N_NODES);
    fill_csr_kernel<<<gE, 256, 0, stream>>>(ei, dinv, cursor, csr_src, csr_coef, N_EDGES);

    // ---- weight/BN prep (fused across layers)
    PrepPtrs p;
    p.g[0] = (const float*)d_in[10]; p.b[0] = (const float*)d_in[11];
    p.m[0] = (const float*)d_in[12]; p.v[0] = (const float*)d_in[13];
    p.g[1] = (const float*)d_in[14]; p.b[1] = (const float*)d_in[15];
    p.m[1] = (const float*)d_in[16]; p.v[1] = (const float*)d_in[17];
    p.g[2] = (const float*)d_in[18]; p.b[2] = (const float*)d_in[19];
    p.m[2] = (const float*)d_in[20]; p.v[2] = (const float*)d_in[21];
    p.W[0] = W1; p.W[1] = Wm; p.W[2] = W2;
    p.sc[0] = sc1; p.sc[1] = scm; p.sc[2] = sc2;
    p.sh[0] = sh1; p.sh[1] = shm; p.sh[2] = sh2;
    p.tW[0] = tW1; p.tW[1] = tWm; p.tW[2] = tW2;
    p.wt[0] = wt1; p.wt[1] = wtm; p.wt[2] = wt2;

    bn_prep_all_kernel<<<3, 128, 0, stream>>>(p);
    {
        dim3 g((128 * HDIM + 255) / 256, 3);
        wprep_all_kernel<<<g, 256, 0, stream>>>(p);
    }
    tw_all_kernel<<<3, 128, 0, stream>>>(p);

    int gG128 = (N_NODES * 16 + 255) / 256;   // gather grid, COUT=128
    int gG64  = (N_NODES * 8 + 255) / 256;    // gather grid, COUT=64

    // ---- layer 1
    gemm_mfma_kernel<128><<<gT, 256, 0, stream>>>(x, wt1, tW1, T, N_NODES);
    gather_kernel<128, true><<<gG128, 256, 0, stream>>>(T, dinv, off, cnt, csr_src, csr_coef, b1, res1, N_NODES);

    // ---- layer 2
    gemm_mfma_kernel<128><<<gT, 256, 0, stream>>>(res1, wtm, tWm, Wm ? T : T, N_NODES);
    gather_kernel<128, true><<<gG128, 256, 0, stream>>>(T, dinv, off, cnt, csr_src, csr_coef, bm, res2, N_NODES);

    // ---- layer 3
    gemm_mfma_kernel<64><<<gT, 256, 0, stream>>>(res2, wt2, tW2, T, N_NODES);
    gather_kernel<64, false><<<gG64, 256, 0, stream>>>(T, dinv, off, cnt, csr_src, csr_coef, b2, out, N_NODES);
}